// Round 3
// baseline (268.912 us; speedup 1.0000x reference)
//
#include <hip/hip_runtime.h>

#define D_MODEL 1024
#define D_STATE 16
#define M_ROWS  4096   // B*L
#define SEQ_L   1024
#define NSEG    64
#define LSEG    16     // SEQ_L / NSEG

typedef __bf16 bf16x8 __attribute__((ext_vector_type(8)));
typedef float  f32x4  __attribute__((ext_vector_type(4)));

__device__ __forceinline__ unsigned short f2bf(float f) {
  unsigned int u = __builtin_bit_cast(unsigned int, f);
  u += 0x7fffu + ((u >> 16) & 1u);           // RNE
  return (unsigned short)(u >> 16);
}
__device__ __forceinline__ float bf2f(unsigned short b) {
  unsigned int u = ((unsigned int)b) << 16;
  return __builtin_bit_cast(float, u);
}
__device__ __forceinline__ float load_elem(const void* p, size_t i, int isbf) {
  if (isbf) return bf2f(((const unsigned short*)p)[i]);
  return ((const float*)p)[i];
}

// Decentralized dtype detection: 64 samples of x_in's even u16s per wave.
// bf16 N(0,1): exponent in [100,135] for ~all lanes; fp32 low-mantissa u16s:
// ~uniform, ~9/64 in range. Threshold 32. Wave-uniform result.
__device__ __forceinline__ int is_bf16(const void* x_in) {
  unsigned int v = ((const unsigned short*)x_in)[2 * (threadIdx.x & 63)];
  unsigned int e = (v >> 7) & 0xFFu;
  unsigned long long m = __ballot(e >= 100u && e <= 135u);
  return __popcll(m) >= 32;
}

// async global->LDS, 16B per lane. LDS dest = (wave-uniform base) + lane*16.
__device__ __forceinline__ void gload16(const void* g, void* l) {
  typedef const __attribute__((address_space(1))) unsigned int GU;
  typedef __attribute__((address_space(3))) unsigned int LU;
  __builtin_amdgcn_global_load_lds((GU*)(unsigned long long)g,
                                   (LU*)(unsigned int)(unsigned long long)l,
                                   16, 0, 0);
}

// ---------------- prep: converts AND weight transposes in ONE launch ----------------
// bid <2048: x_in->bf16 | <2128: smalls | <2656: W_x->bf16 raw | >=2656: transposes
// transpose t = bid-2656: op0 W_in (64x32 tiles) [0,2048); op1 W_x cols 1024.. (4x32)
// [2048,2176); op2 W_dt [2176,3200); op3 W_out [3200,4224)
__global__ void prep_kernel(const void* __restrict__ x_in, unsigned short* __restrict__ x_b,
                            const void* __restrict__ W_in, const void* __restrict__ W_x,
                            const void* __restrict__ W_dt, const void* __restrict__ W_out,
                            unsigned short* __restrict__ wx_raw,
                            unsigned short* __restrict__ wt_in, unsigned short* __restrict__ wt_xbc,
                            unsigned short* __restrict__ wt_dt, unsigned short* __restrict__ wt_out,
                            const void* b_dt, const void* A_log, const void* Dp,
                            const void* ln_g, const void* ln_b,
                            float* o_bdt, float* o_a2, float* o_dp,
                            float* o_lng, float* o_lnb) {
  __shared__ float tile[32][33];
  const int isbf = is_bf16(x_in);
  const int bid = blockIdx.x;
  const int tid = threadIdx.x;
  if (bid < 2048 || (bid >= 2128 && bid < 2656)) {   // bulk bf16 conversion, 8 elems/thread
    const void* src; unsigned short* dst; int c;
    if (bid < 2048) { src = x_in; dst = x_b; c = bid * 256 + tid; }
    else { src = W_x; dst = wx_raw; c = (bid - 2128) * 256 + tid; }  // 135168 chunks
    if (isbf) {
      ((uint4*)dst)[c] = ((const uint4*)src)[c];
    } else {
      float4 a = ((const float4*)src)[2 * c];
      float4 b = ((const float4*)src)[2 * c + 1];
      uint4 p;
      p.x = (unsigned int)f2bf(a.x) | ((unsigned int)f2bf(a.y) << 16);
      p.y = (unsigned int)f2bf(a.z) | ((unsigned int)f2bf(a.w) << 16);
      p.z = (unsigned int)f2bf(b.x) | ((unsigned int)f2bf(b.y) << 16);
      p.w = (unsigned int)f2bf(b.z) | ((unsigned int)f2bf(b.w) << 16);
      ((uint4*)dst)[c] = p;
    }
  } else if (bid < 2128) {                   // smalls: 80 blocks, g in 0..20479
    int g = (bid - 2048) * 256 + tid;
    if (g < 1024)              o_bdt[g]          = load_elem(b_dt, g, isbf);
    else if (g < 17408) {
      float v = load_elem(A_log, g - 1024, isbf);
      o_a2[g - 1024] = -expf(v) * 1.4426950408889634f;
    }
    else if (g < 18432)        o_dp[g - 17408]   = load_elem(Dp, g - 17408, isbf);
    else if (g < 19456)        o_lng[g - 18432]  = load_elem(ln_g, g - 18432, isbf);
    else                       o_lnb[g - 19456]  = load_elem(ln_b, g - 19456, isbf);
  } else {                                   // transposes
    int t = bid - 2656;
    const void* src; unsigned short* dst; int ncols, col0, bxx, byy;
    if (t < 2048)      { src = W_in;  dst = wt_in;  ncols = 2048; col0 = 0;
                         bxx = t & 63; byy = t >> 6; }
    else if (t < 2176) { t -= 2048; src = W_x; dst = wt_xbc; ncols = 1056; col0 = 1024;
                         bxx = t & 3; byy = t >> 2; }
    else if (t < 3200) { t -= 2176; src = W_dt; dst = wt_dt; ncols = 1024; col0 = 0;
                         bxx = t & 31; byy = t >> 5; }
    else               { t -= 3200; src = W_out; dst = wt_out; ncols = 1024; col0 = 0;
                         bxx = t & 31; byy = t >> 5; }
    int tx = tid & 31, ty = tid >> 5;        // 32 x 8
    int n0 = col0 + bxx * 32, k0 = byy * 32;
    #pragma unroll
    for (int r = 0; r < 4; ++r) {
      int k = k0 + ty + r * 8;
      int n = n0 + tx;
      float v = (n < ncols) ? load_elem(src, (size_t)k * ncols + n, isbf) : 0.f;
      tile[ty + r * 8][tx] = v;
    }
    __syncthreads();
    #pragma unroll
    for (int r = 0; r < 4; ++r) {
      int n = n0 + ty + r * 8;
      int k = k0 + tx;
      dst[(size_t)(n - col0) * 1024 + k] = f2bf(tile[tx][ty + r * 8]);
    }
  }
}

// ---------------- bf16 MFMA GEMM, 64x128 tile, dist-2 pipelined LDS-DMA -------------
// Round-0-proven config (best measured): 4 waves x 32x64 sub-tile, 3 LDS buffers
// (36KB -> 4 blocks/CU), dist-2, vmcnt(3). Latency-bound regime: TLP > tile ratio
// (128^2 retiles regressed in R1/R2).
// NEW: XCD-chunked block swizzle (T1). Linear block id -> swz = (lid&7)*(nwg/8) +
// (lid>>3): XCD k executes a contiguous tile range -> B-panels L2-resident per XCD
// (MODE 4: exactly one W_out panel per XCD). Attacks the measured 3x re-fetch
// (G1 FETCH 44MB vs 16MB unique) = the load latency the pipeline can't hide.
// MODE 1: bx<64: n<1024 -> x_bf; else silu -> s_bf. bx>=64: U-composition
//         rides along: C = wt_dt x wx_raw -> U_bf (bf16).   [grid 72x16]
// MODE 2: n<1024 -> softplus(v+aux[n]) -> delta_bf; n<1040 B f32; n<1056 C f32.
//         by==8 reads o2 (wt_xbc) rows n-1024.              [grid 64x9]
// MODE 4: o0 = f32 (v + x_in[m,n]), x_in raw (auxv), self-detected dtype
template<int MODE>
__global__ __launch_bounds__(256, 4) void gemm_bf(
    const unsigned short* __restrict__ A, const unsigned short* __restrict__ Bt, int ldb,
    void* __restrict__ o0, void* __restrict__ o1, void* __restrict__ o2,
    float* __restrict__ o3, float* __restrict__ o4,
    const float* __restrict__ aux, const void* __restrict__ auxv,
    const unsigned short* __restrict__ A_u, const unsigned short* __restrict__ B_u,
    int ldb_u, void* __restrict__ o_u) {
  __shared__ __align__(16) unsigned short a_lds[3][64 * 32];    // 12 KB
  __shared__ __align__(16) unsigned short b_lds[3][128 * 32];   // 24 KB
  const int isbf = (MODE == 4) ? is_bf16(auxv) : 0;
  const int tid = threadIdx.x;
  const int wave = tid >> 6, lane = tid & 63;
  const int wr = (wave >> 1) * 32, wc = (wave & 1) * 64;   // wave -> 32x64 sub-tile
  const int lrow = lane & 15, quad = lane >> 4;

  // XCD-chunked swizzle (bijective: nwg % 8 == 0 for all modes)
  constexpr int GX  = (MODE == 1) ? 72 : 64;
  constexpr int NWG = (MODE == 1) ? 1152 : (MODE == 2) ? 576 : 512;
  constexpr int CPX = NWG / 8;
  const int lid = blockIdx.x + GX * blockIdx.y;
  const int swz = (lid & 7) * CPX + (lid >> 3);
  const int bx = swz % GX, by = swz / GX;

  int m0, n0, ldbl = ldb;
  const unsigned short* Asrc = A;
  const unsigned short* Bsrc = Bt;
  bool isU = false;
  if (MODE == 1 && bx >= 64) {               // U rides along G1
    isU = true;
    int u = (bx - 64) * 16 + by;             // 0..127
    m0 = (u >> 3) * 64; n0 = (u & 7) * 128;
    Asrc = A_u; Bsrc = B_u; ldbl = ldb_u;
  } else {
    m0 = bx * 64; n0 = by * 128;
    if (MODE == 2 && n0 >= 1024) { Bsrc = (const unsigned short*)o2; n0 -= 1024; }
  }
  const int nout = (MODE == 2 && Bsrc == (const unsigned short*)o2) ? n0 + 1024 : n0;

  // staging: lane l -> local row l>>2, 16B slot l&3 holding K-chunk
  // (l&3)^((l>>3)&3) (XOR swizzle; frag ds_read_b128 2-way aliased = free).
  const int sc = (lane & 3) ^ ((lane >> 3) & 3);
  const unsigned short* gA  = Asrc + (size_t)(m0 + wave * 16 + (lane >> 2)) * 1024 + sc * 8;
  const unsigned short* gB  = Bsrc + (size_t)(n0 + wave * 32 + (lane >> 2)) * ldbl + sc * 8;
  const unsigned short* gB2 = gB + (size_t)16 * ldbl;
  const int q2 = quad ^ ((lrow >> 1) & 3);

  f32x4 acc[2][4];
  #pragma unroll
  for (int i = 0; i < 2; ++i)
    #pragma unroll
    for (int j = 0; j < 4; ++j)
      #pragma unroll
      for (int r = 0; r < 4; ++r) acc[i][j][r] = 0.f;

  auto issue = [&](int k) {
    unsigned short* ab = a_lds[k % 3] + wave * 16 * 32;
    unsigned short* bb = b_lds[k % 3] + wave * 32 * 32;
    gload16(gA + k * 32, ab);
    gload16(gB + k * 32, bb);
    gload16(gB2 + k * 32, bb + 16 * 32);
  };
  auto compute = [&](int k) {
    const unsigned short* ard = a_lds[k % 3] + (wr + lrow) * 32 + q2 * 8;
    const unsigned short* brd = b_lds[k % 3] + (wc + lrow) * 32 + q2 * 8;
    bf16x8 af[2], bfr[4];
    #pragma unroll
    for (int i = 0; i < 2; ++i) af[i] = *(const bf16x8*)(ard + i * 16 * 32);
    #pragma unroll
    for (int j = 0; j < 4; ++j) bfr[j] = *(const bf16x8*)(brd + j * 16 * 32);
    #pragma unroll
    for (int i = 0; i < 2; ++i)
      #pragma unroll
      for (int j = 0; j < 4; ++j)
        acc[i][j] = __builtin_amdgcn_mfma_f32_16x16x32_bf16(af[i], bfr[j], acc[i][j], 0, 0, 0);
  };

  issue(0);
  issue(1);
  #pragma unroll
  for (int k = 0; k < 31; ++k) {
    asm volatile("s_waitcnt vmcnt(3)" ::: "memory");   // stage k landed, k+1 in flight
    __builtin_amdgcn_s_barrier();
    if (k + 2 < 32) issue(k + 2);
    compute(k);
  }
  asm volatile("s_waitcnt vmcnt(0)" ::: "memory");
  __builtin_amdgcn_s_barrier();
  compute(31);

  // C/D layout: row = quad*4 + r, col = lane&15.
  #pragma unroll
  for (int i = 0; i < 2; ++i) {
    #pragma unroll
    for (int jj = 0; jj < 4; ++jj) {
      #pragma unroll
      for (int r = 0; r < 4; ++r) {
        int m = m0 + wr + i * 16 + quad * 4 + r;
        int n = nout + wc + jj * 16 + lrow;
        float v = acc[i][jj][r];
        if (MODE == 1) {
          if (isU) {
            ((unsigned short*)o_u)[(size_t)m * 1024 + n] = f2bf(v);
          } else if (n < 1024) {
            ((unsigned short*)o0)[(size_t)m * 1024 + n] = f2bf(v);
          } else {
            float sig = 1.f / (1.f + expf(-v));
            ((unsigned short*)o1)[(size_t)m * 1024 + (n - 1024)] = f2bf(v * sig);
          }
        } else if (MODE == 2) {
          if (n < 1024) {
            float t = v + aux[n];
            float sp = (t > 20.f) ? t : log1pf(expf(t));
            ((unsigned short*)o0)[(size_t)m * 1024 + n] = f2bf(sp);
          }
          else if (n < 1040)  o3[(size_t)m * D_STATE + (n - 1024)] = v;
          else if (n < 1056)  o4[(size_t)m * D_STATE + (n - 1040)] = v;
          // n >= 1056: zero-padded columns, discard
        } else {  // MODE 4: residual from raw x_in
          ((float*)o0)[(size_t)m * 1024 + n] =
              v + load_elem(auxv, (size_t)m * 1024 + n, isbf);
        }
      }
    }
  }
}

// ---------------- chunked parallel scan (NSEG=64, LSEG=16) ----------------
template<int PHASE>
__global__ __launch_bounds__(256) void scan_phase(
    const unsigned short* __restrict__ dl_bf, const unsigned short* __restrict__ x_bf,
    const unsigned short* __restrict__ z_bf, const float* __restrict__ Bs,
    const float* __restrict__ Cs, const float* __restrict__ A2g,
    const float* __restrict__ Dpar, const float* __restrict__ hinit,
    float* __restrict__ Hout, float* __restrict__ sdout,
    unsigned short* __restrict__ g) {
  __shared__ float4 bsh[LSEG][4];
  __shared__ float4 csh[LSEG][4];
  const int tid = threadIdx.x;
  const int bid = blockIdx.x;                 // seg(64) x b(4) x dchunk(4) = 1024
  const int seg = bid >> 4;
  const int b = (bid >> 2) & 3;
  const int dc = bid & 3;
  const int d = dc * 256 + tid;
  const int t0 = seg * LSEG;
  const int bd = b * D_MODEL + d;

  if (tid < LSEG * 4) {                       // stage B (and C) segment rows
    int r = tid >> 2, q = tid & 3;
    size_t src = ((size_t)b * SEQ_L + t0 + r) * 4 + q;
    bsh[r][q] = ((const float4*)Bs)[src];
    if (PHASE == 1) csh[r][q] = ((const float4*)Cs)[src];
  }

  float A2r[16];
  {
    const float4* a4 = (const float4*)(A2g + (size_t)d * 16);
    #pragma unroll
    for (int q = 0; q < 4; ++q) {
      float4 v = a4[q];
      A2r[4*q] = v.x; A2r[4*q+1] = v.y; A2r[4*q+2] = v.z; A2r[4*q+3] = v.w;
    }
  }
  float h[16];
  if (PHASE == 1) {
    const float4* h4 = (const float4*)(hinit + (((size_t)seg * 4096) + bd) * 16);
    #pragma unroll
    for (int q = 0; q < 4; ++q) {
      float4 v = h4[q];
      h[4*q] = v.x; h[4*q+1] = v.y; h[4*q+2] = v.z; h[4*q+3] = v.w;
    }
  } else {
    #pragma unroll
    for (int n = 0; n < 16; ++n) h[n] = 0.f;
  }
  const float Dpd = (PHASE == 1) ? Dpar[d] : 0.f;
  float sd = 0.f;
  const size_t base = ((size_t)b * SEQ_L + t0) * D_MODEL + d;
  __syncthreads();

  unsigned short dreg[2][8], xreg[2][8], zreg[2][8];
  #pragma unroll
  for (int t = 0; t < 8; ++t) {
    size_t o = base + (size_t)t * D_MODEL;
    dreg[0][t] = dl_bf[o]; xreg[0][t] = x_bf[o];
    if (PHASE == 1) zreg[0][t] = z_bf[o];
  }
  #pragma unroll
  for (int c = 0; c < LSEG / 8; ++c) {
    const int cur = c & 1, nxt = cur ^ 1;
    if (c < LSEG / 8 - 1) {                   // prefetch next 8 steps
      #pragma unroll
      for (int t = 0; t < 8; ++t) {
        size_t o = base + (size_t)((c + 1) * 8 + t) * D_MODEL;
        dreg[nxt][t] = dl_bf[o]; xreg[nxt][t] = x_bf[o];
        if (PHASE == 1) zreg[nxt][t] = z_bf[o];
      }
    }
    #pragma unroll
    for (int t = 0; t < 8; ++t) {
      const int tt = c * 8 + t;
      float dl = bf2f(dreg[cur][t]);
      float xx = bf2f(xreg[cur][t]);
      float dx = dl * xx;
      sd += dl;
      float4 b0 = bsh[tt][0], b1 = bsh[tt][1], b2 = bsh[tt][2], b3 = bsh[tt][3];
      float bb[16] = {b0.x,b0.y,b0.z,b0.w, b1.x,b1.y,b1.z,b1.w,
                      b2.x,b2.y,b2.z,b2.w, b3.x,b3.y,b3.z,b3.w};
      if (PHASE == 0) {
        #pragma unroll
        for (int n = 0; n < 16; ++n) {
          float dA = exp2f(dl * A2r[n]);
          h[n] = fmaf(dA, h[n], dx * bb[n]);
        }
      } else {
        float4 c0 = csh[tt][0], c1 = csh[tt][1], c2 = csh[tt][2], c3 = csh[tt][3];
        float cc[16] = {c0.x,c0.y,c0.z,c0.w, c1.x,c1.y,c1.z,c1.w,
                        c2.x,c2.y,c2.z,c2.w, c3.x,c3.y,c3.z,c3.w};
        float y = 0.f;
        #pragma unroll
        for (int n = 0; n < 16; ++n) {
          float dA = exp2f(dl * A2r[n]);
          h[n] = fmaf(dA, h[n], dx * bb[n]);
          y = fmaf(h[n], cc[n], y);
        }
        float zz = bf2f(zreg[cur][t]);
        g[base + (size_t)tt * D_MODEL] = f2bf(fmaf(xx, Dpd, y) * zz);
      }
    }
  }
  if (PHASE == 0) {
    float4* ho = (float4*)(Hout + (((size_t)seg * 4096) + bd) * 16);
    #pragma unroll
    for (int q = 0; q < 4; ++q)
      ho[q] = make_float4(h[4*q], h[4*q+1], h[4*q+2], h[4*q+3]);
    sdout[(size_t)seg * 4096 + bd] = sd;
  }
}

// segment-level scan: h_init(s) = P(s-1)*h_init(s-1) + H(s-1), P = exp2(A2*sumdelta)
__global__ __launch_bounds__(256) void scan_phaseB(
    const float* __restrict__ H, const float* __restrict__ sdelta,
    const float* __restrict__ A2g, float* __restrict__ hinit) {
  int gidx = blockIdx.x * 256 + threadIdx.x;   // 65536 = bd(4096) x n(16)
  int bd = gidx >> 4, n = gidx & 15;
  float A2 = A2g[(size_t)(bd & (D_MODEL - 1)) * 16 + n];
  float hp = 0.f;
  #pragma unroll 8
  for (int s = 0; s < NSEG; ++s) {
    size_t idx = ((size_t)s * 4096 + bd) * 16 + n;
    hinit[idx] = hp;
    float P = exp2f(A2 * sdelta[(size_t)s * 4096 + bd]);
    hp = fmaf(P, hp, H[idx]);
  }
}

// ---------------- LayerNorm over D=1024 per row ----------------
__global__ __launch_bounds__(256) void ln_kernel(const float* __restrict__ res,
    const float* __restrict__ lng, const float* __restrict__ lnb,
    void* __restrict__ out, const void* __restrict__ x_in) {
  const int isbf = is_bf16(x_in);
  int row = blockIdx.x, tid = threadIdx.x;
  const float4* r4 = (const float4*)(res + (size_t)row * D_MODEL);
  float4 v = r4[tid];
  float s = v.x + v.y + v.z + v.w;
  float q = v.x * v.x + v.y * v.y + v.z * v.z + v.w * v.w;
  #pragma unroll
  for (int m = 1; m < 64; m <<= 1) { s += __shfl_xor(s, m); q += __shfl_xor(q, m); }
  __shared__ float ss[4], qs[4];
  int w = tid >> 6;
  if ((tid & 63) == 0) { ss[w] = s; qs[w] = q; }
  __syncthreads();
  s = ss[0] + ss[1] + ss[2] + ss[3];
  q = qs[0] + qs[1] + qs[2] + qs[3];
  float mu = s * (1.f / D_MODEL);
  float var = q * (1.f / D_MODEL) - mu * mu;
  float rstd = rsqrtf(var + 1e-5f);
  float4 gg = ((const float4*)lng)[tid];
  float4 bb = ((const float4*)lnb)[tid];
  float o0 = (v.x - mu) * rstd * gg.x + bb.x;
  float o1 = (v.y - mu) * rstd * gg.y + bb.y;
  float o2 = (v.z - mu) * rstd * gg.z + bb.z;
  float o3 = (v.w - mu) * rstd * gg.w + bb.w;
  if (isbf) {
    ushort4 pv;
    pv.x = f2bf(o0); pv.y = f2bf(o1); pv.z = f2bf(o2); pv.w = f2bf(o3);
    ((ushort4*)out)[(size_t)row * 256 + tid] = pv;
  } else {
    ((float4*)out)[(size_t)row * 256 + tid] = make_float4(o0, o1, o2, o3);
  }
}

extern "C" void kernel_launch(void* const* d_in, const int* in_sizes, int n_in,
                              void* d_out, int out_size, void* d_ws, size_t ws_size,
                              hipStream_t stream) {
  (void)in_sizes; (void)n_in; (void)out_size; (void)ws_size;
  const void* x_in  = d_in[0];
  const void* W_in  = d_in[1];
  const void* W_x   = d_in[2];
  const void* W_dt  = d_in[3];
  const void* b_dt  = d_in[4];
  const void* A_log = d_in[5];
  const void* D_par = d_in[6];
  const void* W_out = d_in[7];
  const void* ln_g  = d_in[8];
  const void* ln_b  = d_in[9];

  char* ws = (char*)d_ws;
  size_t off = 0;
  auto alloc = [&](size_t bytes) -> void* {
    void* p = ws + off;
    off += (bytes + 255) & ~(size_t)255;
    return p;
  };
  unsigned short* x_in_b  = (unsigned short*)alloc((size_t)M_ROWS * D_MODEL * 2);
  unsigned short* wx_raw  = (unsigned short*)alloc((size_t)1024 * 1056 * 2);  // W_x bf16 raw
  float* bdt_f            = (float*)alloc(1024 * 4);
  float* a2_f             = (float*)alloc(16384 * 4);
  float* dp_f             = (float*)alloc(1024 * 4);
  float* lng_f            = (float*)alloc(1024 * 4);
  float* lnb_f            = (float*)alloc(1024 * 4);
  unsigned short* wt_in   = (unsigned short*)alloc((size_t)2048 * 1024 * 2);
  unsigned short* wt_xbc  = (unsigned short*)alloc((size_t)128 * 1024 * 2);
  unsigned short* wt_dt   = (unsigned short*)alloc((size_t)1024 * 1024 * 2);
  unsigned short* wt_out  = (unsigned short*)alloc((size_t)1024 * 1024 * 2);
  unsigned short* U_bf    = (unsigned short*)alloc((size_t)1024 * 1024 * 2);  // (Wx_d@W_dt)^T
  unsigned short* x_bf    = (unsigned short*)alloc((size_t)M_ROWS * D_MODEL * 2);
  unsigned short* s_bf    = (unsigned short*)alloc((size_t)M_ROWS * D_MODEL * 2);  // silu(z)
  unsigned short* delta_bf= (unsigned short*)alloc((size_t)M_ROWS * D_MODEL * 2);
  unsigned short* g_bf    = (unsigned short*)alloc((size_t)M_ROWS * D_MODEL * 2);
  float* bssm_f           = (float*)alloc((size_t)M_ROWS * D_STATE * 4);
  float* cssm_f           = (float*)alloc((size_t)M_ROWS * D_STATE * 4);
  float* H_f              = (float*)alloc((size_t)NSEG * 4096 * 16 * 4);
  float* hinit_f          = (float*)alloc((size_t)NSEG * 4096 * 16 * 4);
  float* sdelta_f         = (float*)alloc((size_t)NSEG * 4096 * 4);
  float* res_f = (float*)x_bf;     // alias: x_bf+s_bf (16MB contiguous) consumed by scan1
                                   // before G4 writes res

  // 1. prep: all converts + all transposes (independent work, one launch)
  prep_kernel<<<6880, 256, 0, stream>>>(x_in, x_in_b, W_in, W_x, W_dt, W_out,
                                        wx_raw, wt_in, wt_xbc, wt_dt, wt_out,
                                        b_dt, A_log, D_par, ln_g, ln_b,
                                        bdt_f, a2_f, dp_f, lng_f, lnb_f);

  // 2. G1 (x_in @ W_in -> x, silu(z))  ∥  U-composition (wt_dt x wx_raw -> W_delta^T)
  gemm_bf<1><<<dim3(72, 16), 256, 0, stream>>>(x_in_b, wt_in, 1024,
      x_bf, s_bf, nullptr, nullptr, nullptr, nullptr, nullptr,
      wt_dt, wx_raw, 1056, U_bf);

  // 3. G2': x @ [W_delta | W_bc] -> delta (softplus fused), B, C
  gemm_bf<2><<<dim3(64, 9), 256, 0, stream>>>(x_bf, U_bf, 1024,
      delta_bf, nullptr, wt_xbc, bssm_f, cssm_f, bdt_f, nullptr,
      nullptr, nullptr, 0, nullptr);

  // 4-6. scan
  scan_phase<0><<<1024, 256, 0, stream>>>(delta_bf, x_bf, nullptr, bssm_f, nullptr,
                                          a2_f, nullptr, nullptr, H_f, sdelta_f, nullptr);
  scan_phaseB<<<256, 256, 0, stream>>>(H_f, sdelta_f, a2_f, hinit_f);
  scan_phase<1><<<1024, 256, 0, stream>>>(delta_bf, x_bf, s_bf, bssm_f, cssm_f,
                                          a2_f, dp_f, hinit_f, nullptr, nullptr, g_bf);

  // 7. G4: g @ W_out + x_in -> res
  gemm_bf<4><<<dim3(64, 8), 256, 0, stream>>>(g_bf, wt_out, 1024,
      res_f, nullptr, nullptr, nullptr, nullptr, nullptr, x_in,
      nullptr, nullptr, 0, nullptr);

  // 8. LayerNorm
  ln_kernel<<<4096, 256, 0, stream>>>(res_f, lng_f, lnb_f, d_out, x_in);
}

// Round 4
// 262.911 us; speedup vs baseline: 1.0228x; 1.0228x over previous
//
#include <hip/hip_runtime.h>

#define D_MODEL 1024
#define D_STATE 16
#define M_ROWS  4096   // B*L
#define SEQ_L   1024
#define NSEG    64
#define LSEG    16     // SEQ_L / NSEG

typedef __bf16 bf16x8 __attribute__((ext_vector_type(8)));
typedef float  f32x4  __attribute__((ext_vector_type(4)));

__device__ __forceinline__ unsigned short f2bf(float f) {
  unsigned int u = __builtin_bit_cast(unsigned int, f);
  u += 0x7fffu + ((u >> 16) & 1u);           // RNE
  return (unsigned short)(u >> 16);
}
__device__ __forceinline__ float bf2f(unsigned short b) {
  unsigned int u = ((unsigned int)b) << 16;
  return __builtin_bit_cast(float, u);
}
__device__ __forceinline__ float load_elem(const void* p, size_t i, int isbf) {
  if (isbf) return bf2f(((const unsigned short*)p)[i]);
  return ((const float*)p)[i];
}

// Decentralized dtype detection: 64 samples of x_in's even u16s per wave.
// bf16 N(0,1): exponent in [100,135] for ~all lanes; fp32 low-mantissa u16s:
// ~uniform, ~9/64 in range. Threshold 32. Wave-uniform result.
__device__ __forceinline__ int is_bf16(const void* x_in) {
  unsigned int v = ((const unsigned short*)x_in)[2 * (threadIdx.x & 63)];
  unsigned int e = (v >> 7) & 0xFFu;
  unsigned long long m = __ballot(e >= 100u && e <= 135u);
  return __popcll(m) >= 32;
}

// async global->LDS, 16B per lane. LDS dest = (wave-uniform base) + lane*16.
__device__ __forceinline__ void gload16(const void* g, void* l) {
  typedef const __attribute__((address_space(1))) unsigned int GU;
  typedef __attribute__((address_space(3))) unsigned int LU;
  __builtin_amdgcn_global_load_lds((GU*)(unsigned long long)g,
                                   (LU*)(unsigned int)(unsigned long long)l,
                                   16, 0, 0);
}

// ---------------- prep: converts AND weight transposes in ONE launch ----------------
// bid <2048: x_in->bf16 | <2128: smalls | <2656: W_x->bf16 raw | >=2656: transposes
// transpose t = bid-2656: op0 W_in (64x32 tiles) [0,2048); op1 W_x cols 1024.. (4x32)
// [2048,2176); op2 W_dt [2176,3200); op3 W_out [3200,4224)
__global__ void prep_kernel(const void* __restrict__ x_in, unsigned short* __restrict__ x_b,
                            const void* __restrict__ W_in, const void* __restrict__ W_x,
                            const void* __restrict__ W_dt, const void* __restrict__ W_out,
                            unsigned short* __restrict__ wx_raw,
                            unsigned short* __restrict__ wt_in, unsigned short* __restrict__ wt_xbc,
                            unsigned short* __restrict__ wt_dt, unsigned short* __restrict__ wt_out,
                            const void* b_dt, const void* A_log, const void* Dp,
                            const void* ln_g, const void* ln_b,
                            float* o_bdt, float* o_a2, float* o_dp,
                            float* o_lng, float* o_lnb) {
  __shared__ float tile[32][33];
  const int isbf = is_bf16(x_in);
  const int bid = blockIdx.x;
  const int tid = threadIdx.x;
  if (bid < 2048 || (bid >= 2128 && bid < 2656)) {   // bulk bf16 conversion, 8 elems/thread
    const void* src; unsigned short* dst; int c;
    if (bid < 2048) { src = x_in; dst = x_b; c = bid * 256 + tid; }
    else { src = W_x; dst = wx_raw; c = (bid - 2128) * 256 + tid; }  // 135168 chunks
    if (isbf) {
      ((uint4*)dst)[c] = ((const uint4*)src)[c];
    } else {
      float4 a = ((const float4*)src)[2 * c];
      float4 b = ((const float4*)src)[2 * c + 1];
      uint4 p;
      p.x = (unsigned int)f2bf(a.x) | ((unsigned int)f2bf(a.y) << 16);
      p.y = (unsigned int)f2bf(a.z) | ((unsigned int)f2bf(a.w) << 16);
      p.z = (unsigned int)f2bf(b.x) | ((unsigned int)f2bf(b.y) << 16);
      p.w = (unsigned int)f2bf(b.z) | ((unsigned int)f2bf(b.w) << 16);
      ((uint4*)dst)[c] = p;
    }
  } else if (bid < 2128) {                   // smalls: 80 blocks, g in 0..20479
    int g = (bid - 2048) * 256 + tid;
    if (g < 1024)              o_bdt[g]          = load_elem(b_dt, g, isbf);
    else if (g < 17408) {
      float v = load_elem(A_log, g - 1024, isbf);
      o_a2[g - 1024] = -expf(v) * 1.4426950408889634f;
    }
    else if (g < 18432)        o_dp[g - 17408]   = load_elem(Dp, g - 17408, isbf);
    else if (g < 19456)        o_lng[g - 18432]  = load_elem(ln_g, g - 18432, isbf);
    else                       o_lnb[g - 19456]  = load_elem(ln_b, g - 19456, isbf);
  } else {                                   // transposes
    int t = bid - 2656;
    const void* src; unsigned short* dst; int ncols, col0, bxx, byy;
    if (t < 2048)      { src = W_in;  dst = wt_in;  ncols = 2048; col0 = 0;
                         bxx = t & 63; byy = t >> 6; }
    else if (t < 2176) { t -= 2048; src = W_x; dst = wt_xbc; ncols = 1056; col0 = 1024;
                         bxx = t & 3; byy = t >> 2; }
    else if (t < 3200) { t -= 2176; src = W_dt; dst = wt_dt; ncols = 1024; col0 = 0;
                         bxx = t & 31; byy = t >> 5; }
    else               { t -= 3200; src = W_out; dst = wt_out; ncols = 1024; col0 = 0;
                         bxx = t & 31; byy = t >> 5; }
    int tx = tid & 31, ty = tid >> 5;        // 32 x 8
    int n0 = col0 + bxx * 32, k0 = byy * 32;
    #pragma unroll
    for (int r = 0; r < 4; ++r) {
      int k = k0 + ty + r * 8;
      int n = n0 + tx;
      float v = (n < ncols) ? load_elem(src, (size_t)k * ncols + n, isbf) : 0.f;
      tile[ty + r * 8][tx] = v;
    }
    __syncthreads();
    #pragma unroll
    for (int r = 0; r < 4; ++r) {
      int n = n0 + ty + r * 8;
      int k = k0 + tx;
      dst[(size_t)(n - col0) * 1024 + k] = f2bf(tile[tx][ty + r * 8]);
    }
  }
}

// ---------------- bf16 MFMA GEMM, 64x128 tile, dist-2 pipelined LDS-DMA -------------
// Round-0-proven config: 4 waves x 32x64 sub-tile, 3 LDS buffers (36KB -> 4 blocks/CU),
// dist-2, vmcnt(3).
// NEW (R4): TRANSPOSED grid. Launch dim3(NPANELS, NTILES_M); bx = blockIdx.y,
// by = blockIdx.x. Linear dispatch order now shares one A-tile (128KB) across all
// consecutive N-panel blocks -> A fetched from HBM once (was once per panel: the
// measured 2.75-3.6x FETCH inflation on G1/G2); B (2-4MB) chip-resident after warmup.
// Turns the staging loads into L2/L3 hits that dist-2 can actually cover.
// MODE 1: bx<64: n<1024 -> x_bf; else silu -> s_bf. bx>=64: U-composition
//         rides along: C = wt_dt x wx_raw -> U_bf (bf16).   [grid 16x72]
// MODE 2: n<1024 -> softplus(v+aux[n]) -> delta_bf; n<1040 B f32; n<1056 C f32.
//         by==8 reads o2 (wt_xbc) rows n-1024.              [grid 9x64]
// MODE 4: o0 = f32 (v + x_in[m,n]), x_in raw (auxv), self-detected dtype  [grid 8x64]
template<int MODE>
__global__ __launch_bounds__(256, 4) void gemm_bf(
    const unsigned short* __restrict__ A, const unsigned short* __restrict__ Bt, int ldb,
    void* __restrict__ o0, void* __restrict__ o1, void* __restrict__ o2,
    float* __restrict__ o3, float* __restrict__ o4,
    const float* __restrict__ aux, const void* __restrict__ auxv,
    const unsigned short* __restrict__ A_u, const unsigned short* __restrict__ B_u,
    int ldb_u, void* __restrict__ o_u) {
  __shared__ __align__(16) unsigned short a_lds[3][64 * 32];    // 12 KB
  __shared__ __align__(16) unsigned short b_lds[3][128 * 32];   // 24 KB
  const int isbf = (MODE == 4) ? is_bf16(auxv) : 0;
  const int tid = threadIdx.x;
  const int wave = tid >> 6, lane = tid & 63;
  const int wr = (wave >> 1) * 32, wc = (wave & 1) * 64;   // wave -> 32x64 sub-tile
  const int lrow = lane & 15, quad = lane >> 4;

  // transposed grid: consecutive linear blocks share the A-tile (bx)
  const int bx = blockIdx.y, by = blockIdx.x;

  int m0, n0, ldbl = ldb;
  const unsigned short* Asrc = A;
  const unsigned short* Bsrc = Bt;
  bool isU = false;
  if (MODE == 1 && bx >= 64) {               // U rides along G1 (dispatched last)
    isU = true;
    int u = (bx - 64) * 16 + by;             // 0..127
    m0 = (u >> 3) * 64; n0 = (u & 7) * 128;
    Asrc = A_u; Bsrc = B_u; ldbl = ldb_u;
  } else {
    m0 = bx * 64; n0 = by * 128;
    if (MODE == 2 && n0 >= 1024) { Bsrc = (const unsigned short*)o2; n0 -= 1024; }
  }
  const int nout = (MODE == 2 && Bsrc == (const unsigned short*)o2) ? n0 + 1024 : n0;

  // staging: lane l -> local row l>>2, 16B slot l&3 holding K-chunk
  // (l&3)^((l>>3)&3) (XOR swizzle; frag ds_read_b128 2-way aliased = free).
  const int sc = (lane & 3) ^ ((lane >> 3) & 3);
  const unsigned short* gA  = Asrc + (size_t)(m0 + wave * 16 + (lane >> 2)) * 1024 + sc * 8;
  const unsigned short* gB  = Bsrc + (size_t)(n0 + wave * 32 + (lane >> 2)) * ldbl + sc * 8;
  const unsigned short* gB2 = gB + (size_t)16 * ldbl;
  const int q2 = quad ^ ((lrow >> 1) & 3);

  f32x4 acc[2][4];
  #pragma unroll
  for (int i = 0; i < 2; ++i)
    #pragma unroll
    for (int j = 0; j < 4; ++j)
      #pragma unroll
      for (int r = 0; r < 4; ++r) acc[i][j][r] = 0.f;

  auto issue = [&](int k) {
    unsigned short* ab = a_lds[k % 3] + wave * 16 * 32;
    unsigned short* bb = b_lds[k % 3] + wave * 32 * 32;
    gload16(gA + k * 32, ab);
    gload16(gB + k * 32, bb);
    gload16(gB2 + k * 32, bb + 16 * 32);
  };
  auto compute = [&](int k) {
    const unsigned short* ard = a_lds[k % 3] + (wr + lrow) * 32 + q2 * 8;
    const unsigned short* brd = b_lds[k % 3] + (wc + lrow) * 32 + q2 * 8;
    bf16x8 af[2], bfr[4];
    #pragma unroll
    for (int i = 0; i < 2; ++i) af[i] = *(const bf16x8*)(ard + i * 16 * 32);
    #pragma unroll
    for (int j = 0; j < 4; ++j) bfr[j] = *(const bf16x8*)(brd + j * 16 * 32);
    #pragma unroll
    for (int i = 0; i < 2; ++i)
      #pragma unroll
      for (int j = 0; j < 4; ++j)
        acc[i][j] = __builtin_amdgcn_mfma_f32_16x16x32_bf16(af[i], bfr[j], acc[i][j], 0, 0, 0);
  };

  issue(0);
  issue(1);
  #pragma unroll
  for (int k = 0; k < 31; ++k) {
    asm volatile("s_waitcnt vmcnt(3)" ::: "memory");   // stage k landed, k+1 in flight
    __builtin_amdgcn_s_barrier();
    if (k + 2 < 32) issue(k + 2);
    compute(k);
  }
  asm volatile("s_waitcnt vmcnt(0)" ::: "memory");
  __builtin_amdgcn_s_barrier();
  compute(31);

  // C/D layout: row = quad*4 + r, col = lane&15.
  #pragma unroll
  for (int i = 0; i < 2; ++i) {
    #pragma unroll
    for (int jj = 0; jj < 4; ++jj) {
      #pragma unroll
      for (int r = 0; r < 4; ++r) {
        int m = m0 + wr + i * 16 + quad * 4 + r;
        int n = nout + wc + jj * 16 + lrow;
        float v = acc[i][jj][r];
        if (MODE == 1) {
          if (isU) {
            ((unsigned short*)o_u)[(size_t)m * 1024 + n] = f2bf(v);
          } else if (n < 1024) {
            ((unsigned short*)o0)[(size_t)m * 1024 + n] = f2bf(v);
          } else {
            float sig = 1.f / (1.f + expf(-v));
            ((unsigned short*)o1)[(size_t)m * 1024 + (n - 1024)] = f2bf(v * sig);
          }
        } else if (MODE == 2) {
          if (n < 1024) {
            float t = v + aux[n];
            float sp = (t > 20.f) ? t : log1pf(expf(t));
            ((unsigned short*)o0)[(size_t)m * 1024 + n] = f2bf(sp);
          }
          else if (n < 1040)  o3[(size_t)m * D_STATE + (n - 1024)] = v;
          else if (n < 1056)  o4[(size_t)m * D_STATE + (n - 1040)] = v;
          // n >= 1056: zero-padded columns, discard
        } else {  // MODE 4: residual from raw x_in
          ((float*)o0)[(size_t)m * 1024 + n] =
              v + load_elem(auxv, (size_t)m * 1024 + n, isbf);
        }
      }
    }
  }
}

// ---------------- chunked parallel scan (NSEG=64, LSEG=16) ----------------
template<int PHASE>
__global__ __launch_bounds__(256) void scan_phase(
    const unsigned short* __restrict__ dl_bf, const unsigned short* __restrict__ x_bf,
    const unsigned short* __restrict__ z_bf, const float* __restrict__ Bs,
    const float* __restrict__ Cs, const float* __restrict__ A2g,
    const float* __restrict__ Dpar, const float* __restrict__ hinit,
    float* __restrict__ Hout, float* __restrict__ sdout,
    unsigned short* __restrict__ g) {
  __shared__ float4 bsh[LSEG][4];
  __shared__ float4 csh[LSEG][4];
  const int tid = threadIdx.x;
  const int bid = blockIdx.x;                 // seg(64) x b(4) x dchunk(4) = 1024
  const int seg = bid >> 4;
  const int b = (bid >> 2) & 3;
  const int dc = bid & 3;
  const int d = dc * 256 + tid;
  const int t0 = seg * LSEG;
  const int bd = b * D_MODEL + d;

  if (tid < LSEG * 4) {                       // stage B (and C) segment rows
    int r = tid >> 2, q = tid & 3;
    size_t src = ((size_t)b * SEQ_L + t0 + r) * 4 + q;
    bsh[r][q] = ((const float4*)Bs)[src];
    if (PHASE == 1) csh[r][q] = ((const float4*)Cs)[src];
  }

  float A2r[16];
  {
    const float4* a4 = (const float4*)(A2g + (size_t)d * 16);
    #pragma unroll
    for (int q = 0; q < 4; ++q) {
      float4 v = a4[q];
      A2r[4*q] = v.x; A2r[4*q+1] = v.y; A2r[4*q+2] = v.z; A2r[4*q+3] = v.w;
    }
  }
  float h[16];
  if (PHASE == 1) {
    const float4* h4 = (const float4*)(hinit + (((size_t)seg * 4096) + bd) * 16);
    #pragma unroll
    for (int q = 0; q < 4; ++q) {
      float4 v = h4[q];
      h[4*q] = v.x; h[4*q+1] = v.y; h[4*q+2] = v.z; h[4*q+3] = v.w;
    }
  } else {
    #pragma unroll
    for (int n = 0; n < 16; ++n) h[n] = 0.f;
  }
  const float Dpd = (PHASE == 1) ? Dpar[d] : 0.f;
  float sd = 0.f;
  const size_t base = ((size_t)b * SEQ_L + t0) * D_MODEL + d;
  __syncthreads();

  unsigned short dreg[2][8], xreg[2][8], zreg[2][8];
  #pragma unroll
  for (int t = 0; t < 8; ++t) {
    size_t o = base + (size_t)t * D_MODEL;
    dreg[0][t] = dl_bf[o]; xreg[0][t] = x_bf[o];
    if (PHASE == 1) zreg[0][t] = z_bf[o];
  }
  #pragma unroll
  for (int c = 0; c < LSEG / 8; ++c) {
    const int cur = c & 1, nxt = cur ^ 1;
    if (c < LSEG / 8 - 1) {                   // prefetch next 8 steps
      #pragma unroll
      for (int t = 0; t < 8; ++t) {
        size_t o = base + (size_t)((c + 1) * 8 + t) * D_MODEL;
        dreg[nxt][t] = dl_bf[o]; xreg[nxt][t] = x_bf[o];
        if (PHASE == 1) zreg[nxt][t] = z_bf[o];
      }
    }
    #pragma unroll
    for (int t = 0; t < 8; ++t) {
      const int tt = c * 8 + t;
      float dl = bf2f(dreg[cur][t]);
      float xx = bf2f(xreg[cur][t]);
      float dx = dl * xx;
      sd += dl;
      float4 b0 = bsh[tt][0], b1 = bsh[tt][1], b2 = bsh[tt][2], b3 = bsh[tt][3];
      float bb[16] = {b0.x,b0.y,b0.z,b0.w, b1.x,b1.y,b1.z,b1.w,
                      b2.x,b2.y,b2.z,b2.w, b3.x,b3.y,b3.z,b3.w};
      if (PHASE == 0) {
        #pragma unroll
        for (int n = 0; n < 16; ++n) {
          float dA = exp2f(dl * A2r[n]);
          h[n] = fmaf(dA, h[n], dx * bb[n]);
        }
      } else {
        float4 c0 = csh[tt][0], c1 = csh[tt][1], c2 = csh[tt][2], c3 = csh[tt][3];
        float cc[16] = {c0.x,c0.y,c0.z,c0.w, c1.x,c1.y,c1.z,c1.w,
                        c2.x,c2.y,c2.z,c2.w, c3.x,c3.y,c3.z,c3.w};
        float y = 0.f;
        #pragma unroll
        for (int n = 0; n < 16; ++n) {
          float dA = exp2f(dl * A2r[n]);
          h[n] = fmaf(dA, h[n], dx * bb[n]);
          y = fmaf(h[n], cc[n], y);
        }
        float zz = bf2f(zreg[cur][t]);
        g[base + (size_t)tt * D_MODEL] = f2bf(fmaf(xx, Dpd, y) * zz);
      }
    }
  }
  if (PHASE == 0) {
    float4* ho = (float4*)(Hout + (((size_t)seg * 4096) + bd) * 16);
    #pragma unroll
    for (int q = 0; q < 4; ++q)
      ho[q] = make_float4(h[4*q], h[4*q+1], h[4*q+2], h[4*q+3]);
    sdout[(size_t)seg * 4096 + bd] = sd;
  }
}

// segment-level scan: h_init(s) = P(s-1)*h_init(s-1) + H(s-1), P = exp2(A2*sumdelta)
__global__ __launch_bounds__(256) void scan_phaseB(
    const float* __restrict__ H, const float* __restrict__ sdelta,
    const float* __restrict__ A2g, float* __restrict__ hinit) {
  int gidx = blockIdx.x * 256 + threadIdx.x;   // 65536 = bd(4096) x n(16)
  int bd = gidx >> 4, n = gidx & 15;
  float A2 = A2g[(size_t)(bd & (D_MODEL - 1)) * 16 + n];
  float hp = 0.f;
  #pragma unroll 8
  for (int s = 0; s < NSEG; ++s) {
    size_t idx = ((size_t)s * 4096 + bd) * 16 + n;
    hinit[idx] = hp;
    float P = exp2f(A2 * sdelta[(size_t)s * 4096 + bd]);
    hp = fmaf(P, hp, H[idx]);
  }
}

// ---------------- LayerNorm over D=1024 per row ----------------
__global__ __launch_bounds__(256) void ln_kernel(const float* __restrict__ res,
    const float* __restrict__ lng, const float* __restrict__ lnb,
    void* __restrict__ out, const void* __restrict__ x_in) {
  const int isbf = is_bf16(x_in);
  int row = blockIdx.x, tid = threadIdx.x;
  const float4* r4 = (const float4*)(res + (size_t)row * D_MODEL);
  float4 v = r4[tid];
  float s = v.x + v.y + v.z + v.w;
  float q = v.x * v.x + v.y * v.y + v.z * v.z + v.w * v.w;
  #pragma unroll
  for (int m = 1; m < 64; m <<= 1) { s += __shfl_xor(s, m); q += __shfl_xor(q, m); }
  __shared__ float ss[4], qs[4];
  int w = tid >> 6;
  if ((tid & 63) == 0) { ss[w] = s; qs[w] = q; }
  __syncthreads();
  s = ss[0] + ss[1] + ss[2] + ss[3];
  q = qs[0] + qs[1] + qs[2] + qs[3];
  float mu = s * (1.f / D_MODEL);
  float var = q * (1.f / D_MODEL) - mu * mu;
  float rstd = rsqrtf(var + 1e-5f);
  float4 gg = ((const float4*)lng)[tid];
  float4 bb = ((const float4*)lnb)[tid];
  float o0 = (v.x - mu) * rstd * gg.x + bb.x;
  float o1 = (v.y - mu) * rstd * gg.y + bb.y;
  float o2 = (v.z - mu) * rstd * gg.z + bb.z;
  float o3 = (v.w - mu) * rstd * gg.w + bb.w;
  if (isbf) {
    ushort4 pv;
    pv.x = f2bf(o0); pv.y = f2bf(o1); pv.z = f2bf(o2); pv.w = f2bf(o3);
    ((ushort4*)out)[(size_t)row * 256 + tid] = pv;
  } else {
    ((float4*)out)[(size_t)row * 256 + tid] = make_float4(o0, o1, o2, o3);
  }
}

extern "C" void kernel_launch(void* const* d_in, const int* in_sizes, int n_in,
                              void* d_out, int out_size, void* d_ws, size_t ws_size,
                              hipStream_t stream) {
  (void)in_sizes; (void)n_in; (void)out_size; (void)ws_size;
  const void* x_in  = d_in[0];
  const void* W_in  = d_in[1];
  const void* W_x   = d_in[2];
  const void* W_dt  = d_in[3];
  const void* b_dt  = d_in[4];
  const void* A_log = d_in[5];
  const void* D_par = d_in[6];
  const void* W_out = d_in[7];
  const void* ln_g  = d_in[8];
  const void* ln_b  = d_in[9];

  char* ws = (char*)d_ws;
  size_t off = 0;
  auto alloc = [&](size_t bytes) -> void* {
    void* p = ws + off;
    off += (bytes + 255) & ~(size_t)255;
    return p;
  };
  unsigned short* x_in_b  = (unsigned short*)alloc((size_t)M_ROWS * D_MODEL * 2);
  unsigned short* wx_raw  = (unsigned short*)alloc((size_t)1024 * 1056 * 2);  // W_x bf16 raw
  float* bdt_f            = (float*)alloc(1024 * 4);
  float* a2_f             = (float*)alloc(16384 * 4);
  float* dp_f             = (float*)alloc(1024 * 4);
  float* lng_f            = (float*)alloc(1024 * 4);
  float* lnb_f            = (float*)alloc(1024 * 4);
  unsigned short* wt_in   = (unsigned short*)alloc((size_t)2048 * 1024 * 2);
  unsigned short* wt_xbc  = (unsigned short*)alloc((size_t)128 * 1024 * 2);
  unsigned short* wt_dt   = (unsigned short*)alloc((size_t)1024 * 1024 * 2);
  unsigned short* wt_out  = (unsigned short*)alloc((size_t)1024 * 1024 * 2);
  unsigned short* U_bf    = (unsigned short*)alloc((size_t)1024 * 1024 * 2);  // (Wx_d@W_dt)^T
  unsigned short* x_bf    = (unsigned short*)alloc((size_t)M_ROWS * D_MODEL * 2);
  unsigned short* s_bf    = (unsigned short*)alloc((size_t)M_ROWS * D_MODEL * 2);  // silu(z)
  unsigned short* delta_bf= (unsigned short*)alloc((size_t)M_ROWS * D_MODEL * 2);
  unsigned short* g_bf    = (unsigned short*)alloc((size_t)M_ROWS * D_MODEL * 2);
  float* bssm_f           = (float*)alloc((size_t)M_ROWS * D_STATE * 4);
  float* cssm_f           = (float*)alloc((size_t)M_ROWS * D_STATE * 4);
  float* H_f              = (float*)alloc((size_t)NSEG * 4096 * 16 * 4);
  float* hinit_f          = (float*)alloc((size_t)NSEG * 4096 * 16 * 4);
  float* sdelta_f         = (float*)alloc((size_t)NSEG * 4096 * 4);
  float* res_f = (float*)x_bf;     // alias: x_bf+s_bf (16MB contiguous) consumed by scan1
                                   // before G4 writes res

  // 1. prep: all converts + all transposes (independent work, one launch)
  prep_kernel<<<6880, 256, 0, stream>>>(x_in, x_in_b, W_in, W_x, W_dt, W_out,
                                        wx_raw, wt_in, wt_xbc, wt_dt, wt_out,
                                        b_dt, A_log, D_par, ln_g, ln_b,
                                        bdt_f, a2_f, dp_f, lng_f, lnb_f);

  // 2. G1 (x_in @ W_in -> x, silu(z))  ∥  U-composition (wt_dt x wx_raw -> W_delta^T)
  //    transposed grid: (by=16, bx=72)
  gemm_bf<1><<<dim3(16, 72), 256, 0, stream>>>(x_in_b, wt_in, 1024,
      x_bf, s_bf, nullptr, nullptr, nullptr, nullptr, nullptr,
      wt_dt, wx_raw, 1056, U_bf);

  // 3. G2': x @ [W_delta | W_bc] -> delta (softplus fused), B, C   (by=9, bx=64)
  gemm_bf<2><<<dim3(9, 64), 256, 0, stream>>>(x_bf, U_bf, 1024,
      delta_bf, nullptr, wt_xbc, bssm_f, cssm_f, bdt_f, nullptr,
      nullptr, nullptr, 0, nullptr);

  // 4-6. scan
  scan_phase<0><<<1024, 256, 0, stream>>>(delta_bf, x_bf, nullptr, bssm_f, nullptr,
                                          a2_f, nullptr, nullptr, H_f, sdelta_f, nullptr);
  scan_phaseB<<<256, 256, 0, stream>>>(H_f, sdelta_f, a2_f, hinit_f);
  scan_phase<1><<<1024, 256, 0, stream>>>(delta_bf, x_bf, s_bf, bssm_f, cssm_f,
                                          a2_f, dp_f, hinit_f, nullptr, nullptr, g_bf);

  // 7. G4: g @ W_out + x_in -> res   (by=8, bx=64)
  gemm_bf<4><<<dim3(8, 64), 256, 0, stream>>>(g_bf, wt_out, 1024,
      res_f, nullptr, nullptr, nullptr, nullptr, nullptr, x_in,
      nullptr, nullptr, 0, nullptr);

  // 8. LayerNorm
  ln_kernel<<<4096, 256, 0, stream>>>(res_f, lng_f, lnb_f, d_out, x_in);
}

// Round 5
// 251.598 us; speedup vs baseline: 1.0688x; 1.0450x over previous
//
#include <hip/hip_runtime.h>

#define D_MODEL 1024
#define D_STATE 16
#define M_ROWS  4096   // B*L
#define SEQ_L   1024
#define NSEG    64
#define LSEG    16     // SEQ_L / NSEG

typedef __bf16 bf16x8 __attribute__((ext_vector_type(8)));
typedef float  f32x4  __attribute__((ext_vector_type(4)));

__device__ __forceinline__ unsigned short f2bf(float f) {
  unsigned int u = __builtin_bit_cast(unsigned int, f);
  u += 0x7fffu + ((u >> 16) & 1u);           // RNE
  return (unsigned short)(u >> 16);
}
__device__ __forceinline__ float bf2f(unsigned short b) {
  unsigned int u = ((unsigned int)b) << 16;
  return __builtin_bit_cast(float, u);
}
__device__ __forceinline__ float load_elem(const void* p, size_t i, int isbf) {
  if (isbf) return bf2f(((const unsigned short*)p)[i]);
  return ((const float*)p)[i];
}

// Decentralized dtype detection: 64 samples of x_in's even u16s per wave.
// bf16 N(0,1): exponent in [100,135] for ~all lanes; fp32 low-mantissa u16s:
// ~uniform, ~9/64 in range. Threshold 32. Wave-uniform result.
__device__ __forceinline__ int is_bf16(const void* x_in) {
  unsigned int v = ((const unsigned short*)x_in)[2 * (threadIdx.x & 63)];
  unsigned int e = (v >> 7) & 0xFFu;
  unsigned long long m = __ballot(e >= 100u && e <= 135u);
  return __popcll(m) >= 32;
}

// async global->LDS, 16B per lane. LDS dest = (wave-uniform base) + lane*16.
__device__ __forceinline__ void gload16(const void* g, void* l) {
  typedef const __attribute__((address_space(1))) unsigned int GU;
  typedef __attribute__((address_space(3))) unsigned int LU;
  __builtin_amdgcn_global_load_lds((GU*)(unsigned long long)g,
                                   (LU*)(unsigned int)(unsigned long long)l,
                                   16, 0, 0);
}

// ---------------- prep: converts AND weight transposes in ONE launch ----------------
// bid <2048: x_in->bf16 | <2128: smalls | <2656: W_x->bf16 raw | >=2656: transposes
// transpose t = bid-2656: op0 W_in (64x32 tiles) [0,2048); op1 W_x cols 1024.. (4x32)
// [2048,2176); op2 W_dt [2176,3200); op3 W_out [3200,4224)
__global__ void prep_kernel(const void* __restrict__ x_in, unsigned short* __restrict__ x_b,
                            const void* __restrict__ W_in, const void* __restrict__ W_x,
                            const void* __restrict__ W_dt, const void* __restrict__ W_out,
                            unsigned short* __restrict__ wx_raw,
                            unsigned short* __restrict__ wt_in, unsigned short* __restrict__ wt_xbc,
                            unsigned short* __restrict__ wt_dt, unsigned short* __restrict__ wt_out,
                            const void* b_dt, const void* A_log, const void* Dp,
                            const void* ln_g, const void* ln_b,
                            float* o_bdt, float* o_a2, float* o_dp,
                            float* o_lng, float* o_lnb) {
  __shared__ float tile[32][33];
  const int isbf = is_bf16(x_in);
  const int bid = blockIdx.x;
  const int tid = threadIdx.x;
  if (bid < 2048 || (bid >= 2128 && bid < 2656)) {   // bulk bf16 conversion, 8 elems/thread
    const void* src; unsigned short* dst; int c;
    if (bid < 2048) { src = x_in; dst = x_b; c = bid * 256 + tid; }
    else { src = W_x; dst = wx_raw; c = (bid - 2128) * 256 + tid; }  // 135168 chunks
    if (isbf) {
      ((uint4*)dst)[c] = ((const uint4*)src)[c];
    } else {
      float4 a = ((const float4*)src)[2 * c];
      float4 b = ((const float4*)src)[2 * c + 1];
      uint4 p;
      p.x = (unsigned int)f2bf(a.x) | ((unsigned int)f2bf(a.y) << 16);
      p.y = (unsigned int)f2bf(a.z) | ((unsigned int)f2bf(a.w) << 16);
      p.z = (unsigned int)f2bf(b.x) | ((unsigned int)f2bf(b.y) << 16);
      p.w = (unsigned int)f2bf(b.z) | ((unsigned int)f2bf(b.w) << 16);
      ((uint4*)dst)[c] = p;
    }
  } else if (bid < 2128) {                   // smalls: 80 blocks, g in 0..20479
    int g = (bid - 2048) * 256 + tid;
    if (g < 1024)              o_bdt[g]          = load_elem(b_dt, g, isbf);
    else if (g < 17408) {
      float v = load_elem(A_log, g - 1024, isbf);
      o_a2[g - 1024] = -expf(v) * 1.4426950408889634f;
    }
    else if (g < 18432)        o_dp[g - 17408]   = load_elem(Dp, g - 17408, isbf);
    else if (g < 19456)        o_lng[g - 18432]  = load_elem(ln_g, g - 18432, isbf);
    else                       o_lnb[g - 19456]  = load_elem(ln_b, g - 19456, isbf);
  } else {                                   // transposes
    int t = bid - 2656;
    const void* src; unsigned short* dst; int ncols, col0, bxx, byy;
    if (t < 2048)      { src = W_in;  dst = wt_in;  ncols = 2048; col0 = 0;
                         bxx = t & 63; byy = t >> 6; }
    else if (t < 2176) { t -= 2048; src = W_x; dst = wt_xbc; ncols = 1056; col0 = 1024;
                         bxx = t & 3; byy = t >> 2; }
    else if (t < 3200) { t -= 2176; src = W_dt; dst = wt_dt; ncols = 1024; col0 = 0;
                         bxx = t & 31; byy = t >> 5; }
    else               { t -= 3200; src = W_out; dst = wt_out; ncols = 1024; col0 = 0;
                         bxx = t & 31; byy = t >> 5; }
    int tx = tid & 31, ty = tid >> 5;        // 32 x 8
    int n0 = col0 + bxx * 32, k0 = byy * 32;
    #pragma unroll
    for (int r = 0; r < 4; ++r) {
      int k = k0 + ty + r * 8;
      int n = n0 + tx;
      float v = (n < ncols) ? load_elem(src, (size_t)k * ncols + n, isbf) : 0.f;
      tile[ty + r * 8][tx] = v;
    }
    __syncthreads();
    #pragma unroll
    for (int r = 0; r < 4; ++r) {
      int n = n0 + ty + r * 8;
      int k = k0 + tx;
      dst[(size_t)(n - col0) * 1024 + k] = f2bf(tile[tx][ty + r * 8]);
    }
  }
}

// ---------------- bf16 MFMA GEMM, dist-2 pipelined LDS-DMA (R0-proven base) ---------
// MODE 1 (G1+U): 64x128 tile, R0 config exactly (near its staging-BW ceiling).
// MODE 2/4 (G2/G4): 64x64 tile. R4 insight: G2 at 576 blocks did HALF G1's FLOPs in
//   the SAME time -> TLP-starved, not BW-bound. 64x64 doubles the grid (1088/1024
//   blocks, ~4.25/CU) and halves LDS (24KB -> 6 blocks/CU allowed); extra staging
//   traffic is fine in the latency-bound regime.
// MODE 1: bx<64: n<1024 -> x_bf; else silu -> s_bf. bx>=64: U-composition
//         rides along: C = wt_dt x wx_raw -> U_bf (bf16).   [grid 72x16]
// MODE 2: n<1024 -> softplus(v+aux[n]) -> delta_bf; n<1040 B f32; n<1056 C f32.
//         by==16 reads o2 (wt_xbc) rows n-1024.             [grid 64x17]
// MODE 4: o0 = f32 (v + x_in[m,n]), x_in raw (auxv), self-detected dtype  [grid 64x16]
template<int MODE>
__global__ __launch_bounds__(256, MODE == 1 ? 4 : 6) void gemm_bf(
    const unsigned short* __restrict__ A, const unsigned short* __restrict__ Bt, int ldb,
    void* __restrict__ o0, void* __restrict__ o1, void* __restrict__ o2,
    float* __restrict__ o3, float* __restrict__ o4,
    const float* __restrict__ aux, const void* __restrict__ auxv,
    const unsigned short* __restrict__ A_u, const unsigned short* __restrict__ B_u,
    int ldb_u, void* __restrict__ o_u) {
  constexpr int BN = (MODE == 1) ? 128 : 64;   // tile cols
  constexpr int NJ = BN / 32;                  // col-frags per wave (4 or 2)
  constexpr int BW = BN / 4;                   // B rows staged per wave (32 or 16)
  __shared__ __align__(16) unsigned short a_lds[3][64 * 32];    // 12 KB
  __shared__ __align__(16) unsigned short b_lds[3][BN * 32];    // 24 or 12 KB
  const int isbf = (MODE == 4) ? is_bf16(auxv) : 0;
  const int tid = threadIdx.x;
  const int wave = tid >> 6, lane = tid & 63;
  const int wr = (wave >> 1) * 32, wc = (wave & 1) * (BN / 2);  // wave -> 32x(BN/2)
  const int lrow = lane & 15, quad = lane >> 4;

  const int bx = blockIdx.x, by = blockIdx.y;

  int m0, n0, ldbl = ldb;
  const unsigned short* Asrc = A;
  const unsigned short* Bsrc = Bt;
  bool isU = false;
  if (MODE == 1 && bx >= 64) {               // U rides along G1
    isU = true;
    int u = (bx - 64) * 16 + by;             // 0..127
    m0 = (u >> 3) * 64; n0 = (u & 7) * 128;
    Asrc = A_u; Bsrc = B_u; ldbl = ldb_u;
  } else {
    m0 = bx * 64; n0 = by * BN;
    if (MODE == 2 && n0 >= 1024) { Bsrc = (const unsigned short*)o2; n0 -= 1024; }
  }
  const int nout = (MODE == 2 && Bsrc == (const unsigned short*)o2) ? n0 + 1024 : n0;

  // staging: lane l -> local row l>>2, 16B slot l&3 holding K-chunk
  // (l&3)^((l>>3)&3) (XOR swizzle; frag ds_read_b128 2-way aliased = free).
  const int sc = (lane & 3) ^ ((lane >> 3) & 3);
  const unsigned short* gA  = Asrc + (size_t)(m0 + wave * 16 + (lane >> 2)) * 1024 + sc * 8;
  const unsigned short* gB  = Bsrc + (size_t)(n0 + wave * BW + (lane >> 2)) * ldbl + sc * 8;
  const unsigned short* gB2 = gB + (size_t)16 * ldbl;   // MODE 1 only
  const int q2 = quad ^ ((lrow >> 1) & 3);

  f32x4 acc[2][NJ];
  #pragma unroll
  for (int i = 0; i < 2; ++i)
    #pragma unroll
    for (int j = 0; j < NJ; ++j)
      #pragma unroll
      for (int r = 0; r < 4; ++r) acc[i][j][r] = 0.f;

  auto issue = [&](int k) {
    unsigned short* ab = a_lds[k % 3] + wave * 16 * 32;
    unsigned short* bb = b_lds[k % 3] + wave * BW * 32;
    gload16(gA + k * 32, ab);
    gload16(gB + k * 32, bb);
    if constexpr (MODE == 1) gload16(gB2 + k * 32, bb + 16 * 32);
  };
  auto compute = [&](int k) {
    const unsigned short* ard = a_lds[k % 3] + (wr + lrow) * 32 + q2 * 8;
    const unsigned short* brd = b_lds[k % 3] + (wc + lrow) * 32 + q2 * 8;
    bf16x8 af[2], bfr[NJ];
    #pragma unroll
    for (int i = 0; i < 2; ++i) af[i] = *(const bf16x8*)(ard + i * 16 * 32);
    #pragma unroll
    for (int j = 0; j < NJ; ++j) bfr[j] = *(const bf16x8*)(brd + j * 16 * 32);
    #pragma unroll
    for (int i = 0; i < 2; ++i)
      #pragma unroll
      for (int j = 0; j < NJ; ++j)
        acc[i][j] = __builtin_amdgcn_mfma_f32_16x16x32_bf16(af[i], bfr[j], acc[i][j], 0, 0, 0);
  };

  issue(0);
  issue(1);
  #pragma unroll
  for (int k = 0; k < 31; ++k) {
    if constexpr (MODE == 1)
      asm volatile("s_waitcnt vmcnt(3)" ::: "memory");   // stage k landed, k+1 in flight
    else
      asm volatile("s_waitcnt vmcnt(2)" ::: "memory");   // 2 loads/stage variant
    __builtin_amdgcn_s_barrier();
    if (k + 2 < 32) issue(k + 2);
    compute(k);
  }
  asm volatile("s_waitcnt vmcnt(0)" ::: "memory");
  __builtin_amdgcn_s_barrier();
  compute(31);

  // C/D layout: row = quad*4 + r, col = lane&15.
  #pragma unroll
  for (int i = 0; i < 2; ++i) {
    #pragma unroll
    for (int jj = 0; jj < NJ; ++jj) {
      #pragma unroll
      for (int r = 0; r < 4; ++r) {
        int m = m0 + wr + i * 16 + quad * 4 + r;
        int n = nout + wc + jj * 16 + lrow;
        float v = acc[i][jj][r];
        if (MODE == 1) {
          if (isU) {
            ((unsigned short*)o_u)[(size_t)m * 1024 + n] = f2bf(v);
          } else if (n < 1024) {
            ((unsigned short*)o0)[(size_t)m * 1024 + n] = f2bf(v);
          } else {
            float sig = 1.f / (1.f + expf(-v));
            ((unsigned short*)o1)[(size_t)m * 1024 + (n - 1024)] = f2bf(v * sig);
          }
        } else if (MODE == 2) {
          if (n < 1024) {
            float t = v + aux[n];
            float sp = (t > 20.f) ? t : log1pf(expf(t));
            ((unsigned short*)o0)[(size_t)m * 1024 + n] = f2bf(sp);
          }
          else if (n < 1040)  o3[(size_t)m * D_STATE + (n - 1024)] = v;
          else if (n < 1056)  o4[(size_t)m * D_STATE + (n - 1040)] = v;
          // n >= 1056: zero-padded columns, discard
        } else {  // MODE 4: residual from raw x_in
          ((float*)o0)[(size_t)m * 1024 + n] =
              v + load_elem(auxv, (size_t)m * 1024 + n, isbf);
        }
      }
    }
  }
}

// ---------------- chunked parallel scan (NSEG=64, LSEG=16) ----------------
template<int PHASE>
__global__ __launch_bounds__(256) void scan_phase(
    const unsigned short* __restrict__ dl_bf, const unsigned short* __restrict__ x_bf,
    const unsigned short* __restrict__ z_bf, const float* __restrict__ Bs,
    const float* __restrict__ Cs, const float* __restrict__ A2g,
    const float* __restrict__ Dpar, const float* __restrict__ hinit,
    float* __restrict__ Hout, float* __restrict__ sdout,
    unsigned short* __restrict__ g) {
  __shared__ float4 bsh[LSEG][4];
  __shared__ float4 csh[LSEG][4];
  const int tid = threadIdx.x;
  const int bid = blockIdx.x;                 // seg(64) x b(4) x dchunk(4) = 1024
  const int seg = bid >> 4;
  const int b = (bid >> 2) & 3;
  const int dc = bid & 3;
  const int d = dc * 256 + tid;
  const int t0 = seg * LSEG;
  const int bd = b * D_MODEL + d;

  if (tid < LSEG * 4) {                       // stage B (and C) segment rows
    int r = tid >> 2, q = tid & 3;
    size_t src = ((size_t)b * SEQ_L + t0 + r) * 4 + q;
    bsh[r][q] = ((const float4*)Bs)[src];
    if (PHASE == 1) csh[r][q] = ((const float4*)Cs)[src];
  }

  float A2r[16];
  {
    const float4* a4 = (const float4*)(A2g + (size_t)d * 16);
    #pragma unroll
    for (int q = 0; q < 4; ++q) {
      float4 v = a4[q];
      A2r[4*q] = v.x; A2r[4*q+1] = v.y; A2r[4*q+2] = v.z; A2r[4*q+3] = v.w;
    }
  }
  float h[16];
  if (PHASE == 1) {
    const float4* h4 = (const float4*)(hinit + (((size_t)seg * 4096) + bd) * 16);
    #pragma unroll
    for (int q = 0; q < 4; ++q) {
      float4 v = h4[q];
      h[4*q] = v.x; h[4*q+1] = v.y; h[4*q+2] = v.z; h[4*q+3] = v.w;
    }
  } else {
    #pragma unroll
    for (int n = 0; n < 16; ++n) h[n] = 0.f;
  }
  const float Dpd = (PHASE == 1) ? Dpar[d] : 0.f;
  float sd = 0.f;
  const size_t base = ((size_t)b * SEQ_L + t0) * D_MODEL + d;
  __syncthreads();

  unsigned short dreg[2][8], xreg[2][8], zreg[2][8];
  #pragma unroll
  for (int t = 0; t < 8; ++t) {
    size_t o = base + (size_t)t * D_MODEL;
    dreg[0][t] = dl_bf[o]; xreg[0][t] = x_bf[o];
    if (PHASE == 1) zreg[0][t] = z_bf[o];
  }
  #pragma unroll
  for (int c = 0; c < LSEG / 8; ++c) {
    const int cur = c & 1, nxt = cur ^ 1;
    if (c < LSEG / 8 - 1) {                   // prefetch next 8 steps
      #pragma unroll
      for (int t = 0; t < 8; ++t) {
        size_t o = base + (size_t)((c + 1) * 8 + t) * D_MODEL;
        dreg[nxt][t] = dl_bf[o]; xreg[nxt][t] = x_bf[o];
        if (PHASE == 1) zreg[nxt][t] = z_bf[o];
      }
    }
    #pragma unroll
    for (int t = 0; t < 8; ++t) {
      const int tt = c * 8 + t;
      float dl = bf2f(dreg[cur][t]);
      float xx = bf2f(xreg[cur][t]);
      float dx = dl * xx;
      sd += dl;
      float4 b0 = bsh[tt][0], b1 = bsh[tt][1], b2 = bsh[tt][2], b3 = bsh[tt][3];
      float bb[16] = {b0.x,b0.y,b0.z,b0.w, b1.x,b1.y,b1.z,b1.w,
                      b2.x,b2.y,b2.z,b2.w, b3.x,b3.y,b3.z,b3.w};
      if (PHASE == 0) {
        #pragma unroll
        for (int n = 0; n < 16; ++n) {
          float dA = exp2f(dl * A2r[n]);
          h[n] = fmaf(dA, h[n], dx * bb[n]);
        }
      } else {
        float4 c0 = csh[tt][0], c1 = csh[tt][1], c2 = csh[tt][2], c3 = csh[tt][3];
        float cc[16] = {c0.x,c0.y,c0.z,c0.w, c1.x,c1.y,c1.z,c1.w,
                        c2.x,c2.y,c2.z,c2.w, c3.x,c3.y,c3.z,c3.w};
        float y = 0.f;
        #pragma unroll
        for (int n = 0; n < 16; ++n) {
          float dA = exp2f(dl * A2r[n]);
          h[n] = fmaf(dA, h[n], dx * bb[n]);
          y = fmaf(h[n], cc[n], y);
        }
        float zz = bf2f(zreg[cur][t]);
        g[base + (size_t)tt * D_MODEL] = f2bf(fmaf(xx, Dpd, y) * zz);
      }
    }
  }
  if (PHASE == 0) {
    float4* ho = (float4*)(Hout + (((size_t)seg * 4096) + bd) * 16);
    #pragma unroll
    for (int q = 0; q < 4; ++q)
      ho[q] = make_float4(h[4*q], h[4*q+1], h[4*q+2], h[4*q+3]);
    sdout[(size_t)seg * 4096 + bd] = sd;
  }
}

// segment-level scan: h_init(s) = P(s-1)*h_init(s-1) + H(s-1), P = exp2(A2*sumdelta)
__global__ __launch_bounds__(256) void scan_phaseB(
    const float* __restrict__ H, const float* __restrict__ sdelta,
    const float* __restrict__ A2g, float* __restrict__ hinit) {
  int gidx = blockIdx.x * 256 + threadIdx.x;   // 65536 = bd(4096) x n(16)
  int bd = gidx >> 4, n = gidx & 15;
  float A2 = A2g[(size_t)(bd & (D_MODEL - 1)) * 16 + n];
  float hp = 0.f;
  #pragma unroll 8
  for (int s = 0; s < NSEG; ++s) {
    size_t idx = ((size_t)s * 4096 + bd) * 16 + n;
    hinit[idx] = hp;
    float P = exp2f(A2 * sdelta[(size_t)s * 4096 + bd]);
    hp = fmaf(P, hp, H[idx]);
  }
}

// ---------------- LayerNorm over D=1024 per row ----------------
__global__ __launch_bounds__(256) void ln_kernel(const float* __restrict__ res,
    const float* __restrict__ lng, const float* __restrict__ lnb,
    void* __restrict__ out, const void* __restrict__ x_in) {
  const int isbf = is_bf16(x_in);
  int row = blockIdx.x, tid = threadIdx.x;
  const float4* r4 = (const float4*)(res + (size_t)row * D_MODEL);
  float4 v = r4[tid];
  float s = v.x + v.y + v.z + v.w;
  float q = v.x * v.x + v.y * v.y + v.z * v.z + v.w * v.w;
  #pragma unroll
  for (int m = 1; m < 64; m <<= 1) { s += __shfl_xor(s, m); q += __shfl_xor(q, m); }
  __shared__ float ss[4], qs[4];
  int w = tid >> 6;
  if ((tid & 63) == 0) { ss[w] = s; qs[w] = q; }
  __syncthreads();
  s = ss[0] + ss[1] + ss[2] + ss[3];
  q = qs[0] + qs[1] + qs[2] + qs[3];
  float mu = s * (1.f / D_MODEL);
  float var = q * (1.f / D_MODEL) - mu * mu;
  float rstd = rsqrtf(var + 1e-5f);
  float4 gg = ((const float4*)lng)[tid];
  float4 bb = ((const float4*)lnb)[tid];
  float o0 = (v.x - mu) * rstd * gg.x + bb.x;
  float o1 = (v.y - mu) * rstd * gg.y + bb.y;
  float o2 = (v.z - mu) * rstd * gg.z + bb.z;
  float o3 = (v.w - mu) * rstd * gg.w + bb.w;
  if (isbf) {
    ushort4 pv;
    pv.x = f2bf(o0); pv.y = f2bf(o1); pv.z = f2bf(o2); pv.w = f2bf(o3);
    ((ushort4*)out)[(size_t)row * 256 + tid] = pv;
  } else {
    ((float4*)out)[(size_t)row * 256 + tid] = make_float4(o0, o1, o2, o3);
  }
}

extern "C" void kernel_launch(void* const* d_in, const int* in_sizes, int n_in,
                              void* d_out, int out_size, void* d_ws, size_t ws_size,
                              hipStream_t stream) {
  (void)in_sizes; (void)n_in; (void)out_size; (void)ws_size;
  const void* x_in  = d_in[0];
  const void* W_in  = d_in[1];
  const void* W_x   = d_in[2];
  const void* W_dt  = d_in[3];
  const void* b_dt  = d_in[4];
  const void* A_log = d_in[5];
  const void* D_par = d_in[6];
  const void* W_out = d_in[7];
  const void* ln_g  = d_in[8];
  const void* ln_b  = d_in[9];

  char* ws = (char*)d_ws;
  size_t off = 0;
  auto alloc = [&](size_t bytes) -> void* {
    void* p = ws + off;
    off += (bytes + 255) & ~(size_t)255;
    return p;
  };
  unsigned short* x_in_b  = (unsigned short*)alloc((size_t)M_ROWS * D_MODEL * 2);
  unsigned short* wx_raw  = (unsigned short*)alloc((size_t)1024 * 1056 * 2);  // W_x bf16 raw
  float* bdt_f            = (float*)alloc(1024 * 4);
  float* a2_f             = (float*)alloc(16384 * 4);
  float* dp_f             = (float*)alloc(1024 * 4);
  float* lng_f            = (float*)alloc(1024 * 4);
  float* lnb_f            = (float*)alloc(1024 * 4);
  unsigned short* wt_in   = (unsigned short*)alloc((size_t)2048 * 1024 * 2);
  unsigned short* wt_xbc  = (unsigned short*)alloc((size_t)128 * 1024 * 2);
  unsigned short* wt_dt   = (unsigned short*)alloc((size_t)1024 * 1024 * 2);
  unsigned short* wt_out  = (unsigned short*)alloc((size_t)1024 * 1024 * 2);
  unsigned short* U_bf    = (unsigned short*)alloc((size_t)1024 * 1024 * 2);  // (Wx_d@W_dt)^T
  unsigned short* x_bf    = (unsigned short*)alloc((size_t)M_ROWS * D_MODEL * 2);
  unsigned short* s_bf    = (unsigned short*)alloc((size_t)M_ROWS * D_MODEL * 2);  // silu(z)
  unsigned short* delta_bf= (unsigned short*)alloc((size_t)M_ROWS * D_MODEL * 2);
  unsigned short* g_bf    = (unsigned short*)alloc((size_t)M_ROWS * D_MODEL * 2);
  float* bssm_f           = (float*)alloc((size_t)M_ROWS * D_STATE * 4);
  float* cssm_f           = (float*)alloc((size_t)M_ROWS * D_STATE * 4);
  float* H_f              = (float*)alloc((size_t)NSEG * 4096 * 16 * 4);
  float* hinit_f          = (float*)alloc((size_t)NSEG * 4096 * 16 * 4);
  float* sdelta_f         = (float*)alloc((size_t)NSEG * 4096 * 4);
  float* res_f = (float*)x_bf;     // alias: x_bf+s_bf (16MB contiguous) consumed by scan1
                                   // before G4 writes res

  // 1. prep: all converts + all transposes (independent work, one launch)
  prep_kernel<<<6880, 256, 0, stream>>>(x_in, x_in_b, W_in, W_x, W_dt, W_out,
                                        wx_raw, wt_in, wt_xbc, wt_dt, wt_out,
                                        b_dt, A_log, D_par, ln_g, ln_b,
                                        bdt_f, a2_f, dp_f, lng_f, lnb_f);

  // 2. G1 (x_in @ W_in -> x, silu(z))  ∥  U-composition (wt_dt x wx_raw -> W_delta^T)
  gemm_bf<1><<<dim3(72, 16), 256, 0, stream>>>(x_in_b, wt_in, 1024,
      x_bf, s_bf, nullptr, nullptr, nullptr, nullptr, nullptr,
      wt_dt, wx_raw, 1056, U_bf);

  // 3. G2': x @ [W_delta | W_bc] -> delta (softplus fused), B, C  (64x64 tiles)
  gemm_bf<2><<<dim3(64, 17), 256, 0, stream>>>(x_bf, U_bf, 1024,
      delta_bf, nullptr, wt_xbc, bssm_f, cssm_f, bdt_f, nullptr,
      nullptr, nullptr, 0, nullptr);

  // 4-6. scan
  scan_phase<0><<<1024, 256, 0, stream>>>(delta_bf, x_bf, nullptr, bssm_f, nullptr,
                                          a2_f, nullptr, nullptr, H_f, sdelta_f, nullptr);
  scan_phaseB<<<256, 256, 0, stream>>>(H_f, sdelta_f, a2_f, hinit_f);
  scan_phase<1><<<1024, 256, 0, stream>>>(delta_bf, x_bf, s_bf, bssm_f, cssm_f,
                                          a2_f, dp_f, hinit_f, nullptr, nullptr, g_bf);

  // 7. G4: g @ W_out + x_in -> res  (64x64 tiles)
  gemm_bf<4><<<dim3(64, 16), 256, 0, stream>>>(g_bf, wt_out, 1024,
      res_f, nullptr, nullptr, nullptr, nullptr, nullptr, x_in,
      nullptr, nullptr, 0, nullptr);

  // 8. LayerNorm
  ln_kernel<<<4096, 256, 0, stream>>>(res_f, lng_f, lnb_f, d_out, x_in);
}